// Round 22
// baseline (2088.863 us; speedup 1.0000x reference)
//
#include <hip/hip_runtime.h>

// V=16000 E=512 H=512 L=2 S=128 T=128 B=64; gate dim 4H=2048
// r22 = r21 with the s_sleep constant-arg compile fix:
//  * pipe WGs convert to logits workers after their last step (tail on 256 CUs)
//  * adaptive worker poll backoff (branch to constant sleep 127 / 8)
// Everything else identical to r20 (pipe=r17/r19 logic, GEMM=r18 tile).

typedef __attribute__((ext_vector_type(8))) short v8s;
typedef __attribute__((ext_vector_type(4))) short v4s;
typedef __attribute__((ext_vector_type(8))) _Float16 v8h;
typedef __attribute__((ext_vector_type(4))) float v4f;
typedef __attribute__((ext_vector_type(4))) unsigned int v4u;

#define AS1 __attribute__((address_space(1)))
#define AS3 __attribute__((address_space(3)))

__device__ __forceinline__ short f2h(float x) {
  _Float16 h = (_Float16)x;
  return __builtin_bit_cast(short, h);
}
__device__ __forceinline__ void gload16(const void* g, void* l) {
  __builtin_amdgcn_global_load_lds((const AS1 void*)g, (AS3 void*)l, 16, 0, 0);
}
__device__ __forceinline__ float sigf(float x) { return 1.f / (1.f + __expf(-x)); }
__device__ __forceinline__ float tanhfast(float x) { return 2.f / (1.f + __expf(-2.f * x)) - 1.f; }

__device__ __forceinline__ void ld16_sc1(v4u& d, const void* p) {
  asm volatile("global_load_dwordx4 %0, %1, off sc1" : "=v"(d) : "v"(p) : "memory");
}
__device__ __forceinline__ void ld16(v4u& d, const void* p) {
  asm volatile("global_load_dwordx4 %0, %1, off" : "=v"(d) : "v"(p));
}

// lanes 0..31 check flags[base+lane] >= tgt (packed stride-1)
__device__ __forceinline__ void poll32(const unsigned* flags, int base, unsigned tgt) {
  int lane = threadIdx.x & 63;
  const unsigned* fp = flags + base + (lane & 31);
  while (true) {
    unsigned v;
    asm volatile("global_load_dword %0, %1, off sc1\n\ts_waitcnt vmcnt(0)"
                 : "=v"(v) : "v"(fp) : "memory");
    if (__all((int)((lane >= 32) || (v >= tgt)))) break;
    __builtin_amdgcn_s_sleep(1);
  }
}
// worker poll on L1 flags (packed base 32), adaptive backoff (const sleeps)
__device__ __forceinline__ void poll_l1(const unsigned* flags, unsigned thr) {
  int lane = threadIdx.x & 63;
  const unsigned* fp = flags + 32 + (lane & 31);
  while (true) {
    unsigned v;
    asm volatile("global_load_dword %0, %1, off sc1\n\ts_waitcnt vmcnt(0)"
                 : "=v"(v) : "v"(fp) : "memory");
    if (__all((int)((lane >= 32) || (v >= thr)))) break;
    bool far = !__all((int)((lane >= 32) || (v + 4 >= thr)));
    if (far) __builtin_amdgcn_s_sleep(127);
    else     __builtin_amdgcn_s_sleep(8);
  }
}

// ---------- fused prologue kernels ----------
struct ConvJobs {
  const float* src[8];
  short* dst[8];
  int coloff[8];
};
__global__ void conv8(ConvJobs J) {
  int j = blockIdx.y;
  int i = blockIdx.x * 256 + threadIdx.x;
  int r = i >> 7, k4 = (i & 127) * 4;
  int rr = ((r >> 4) & 31) * 64 + (r >> 9) * 16 + (r & 15);
  float4 v = *(const float4*)(J.src[j] + (size_t)r * 512 + k4);
  v4s s; s[0] = f2h(v.x); s[1] = f2h(v.y); s[2] = f2h(v.z); s[3] = f2h(v.w);
  *(v4s*)(J.dst[j] + (size_t)rr * 1024 + J.coloff[j] + k4) = s;
}

__global__ void conv_ow(const float* __restrict__ in, short* __restrict__ out) {
  int i = blockIdx.x * 256 + threadIdx.x;
  if (i >= 16000 * 128) return;
  int r = i >> 7, k4 = (i & 127) * 4;
  float4 v = *(const float4*)(in + (size_t)r * 512 + k4);
  v4s s; s[0] = f2h(v.x); s[1] = f2h(v.y); s[2] = f2h(v.z); s[3] = f2h(v.w);
  *(v4s*)(out + (size_t)r * 512 + k4) = s;
}

struct BiasJobs {
  const float* a[4];
  const float* b[4];
  float* o[4];
};
__global__ void conv_b4(BiasJobs J) {
  int j = blockIdx.y;
  int r = blockIdx.x * 256 + threadIdx.x;
  if (r < 2048)
    J.o[j][((r >> 4) & 31) * 64 + (r >> 9) * 16 + (r & 15)] = J.a[j][r] + J.b[j][r];
}

__global__ void zero3(short* a, short* b, short* c, unsigned* f) {
  int i = blockIdx.x * 256 + threadIdx.x;
  if (i < 32768) { a[i] = 0; b[i] = 0; c[i] = 0; }
  if (i < 128) f[i] = 0;                    // flags[64] + wq
}

__global__ void embed_all(const int* __restrict__ src, const int* __restrict__ trg,
                          const float* __restrict__ ee, const float* __restrict__ de,
                          short* __restrict__ out) {
  int row = blockIdx.x;
  int e = threadIdx.x * 2;
  const float* emb;
  int id;
  if (row < 8192) { id = src[row]; emb = ee; }
  else { id = trg[row - 8192]; emb = de; }
  float2 v = *(const float2*)(emb + (size_t)id * 512 + e);
  unsigned pack = ((unsigned)(unsigned short)f2h(v.y) << 16) | (unsigned short)f2h(v.x);
  *(unsigned*)(out + (size_t)row * 512 + e) = pack;
}

// ---------- GEMM tile: C[M,N] = A[M,K]*B[N,K]^T (+bias), 128x128, BK=128
#define GF_BIAS 2
#define GF_GUARDM 4
#define SLOT 32768

__device__ __forceinline__ void gemm_tile128(
    const short* Am, const short* Bm, const float* bias, float* Cm,
    int M, int K, int ldc, int tm, int tn, int flags, char* smem) {
  short* lA = (short*)smem;
  short* lB = (short*)(smem + 32768);
  const int tid = threadIdx.x, lane = tid & 63, wave = tid >> 6;
  const int wm = wave >> 1, wn = wave & 1;
  v4f acc[4][4] = {};
  const short* Abase = Am + (size_t)tm * 128 * K;
  const short* Bbase = Bm + (size_t)tn * 128 * K;

  for (int kt = 0; kt < K; kt += 128) {
    __syncthreads();
#pragma unroll
    for (int i2 = 0; i2 < 8; ++i2) {
      int c = (wave * 8 + i2) * 64 + lane;
      int row = c >> 4, ch = c & 15;
      int sch = ch ^ (row & 15);
      gload16(Abase + (size_t)row * K + kt + sch * 8, (char*)lA + c * 16);
      gload16(Bbase + (size_t)row * K + kt + sch * 8, (char*)lB + c * 16);
    }
    asm volatile("s_waitcnt vmcnt(0)" ::: "memory");
    __syncthreads();
#pragma unroll
    for (int kc = 0; kc < 4; ++kc) {
      v8h af[4], bh[4];
#pragma unroll
      for (int mt = 0; mt < 4; ++mt) {
        int row = wm * 64 + mt * 16 + (lane & 15);
        af[mt] = *(const v8h*)((const char*)lA + row * 256 +
                               ((kc * 64 + (lane >> 4) * 16) ^ ((row & 15) << 4)));
      }
#pragma unroll
      for (int nt = 0; nt < 4; ++nt) {
        int row = wn * 64 + nt * 16 + (lane & 15);
        bh[nt] = *(const v8h*)((const char*)lB + row * 256 +
                               ((kc * 64 + (lane >> 4) * 16) ^ ((row & 15) << 4)));
      }
#pragma unroll
      for (int mt = 0; mt < 4; ++mt)
#pragma unroll
        for (int nt = 0; nt < 4; ++nt)
          acc[mt][nt] = __builtin_amdgcn_mfma_f32_16x16x32_f16(af[mt], bh[nt], acc[mt][nt], 0, 0, 0);
    }
  }

  __syncthreads();
  float* ft = (float*)smem;
#pragma unroll
  for (int mt = 0; mt < 4; ++mt)
#pragma unroll
    for (int nt = 0; nt < 4; ++nt)
#pragma unroll
      for (int rg = 0; rg < 4; ++rg) {
        int r = wm * 64 + mt * 16 + (lane >> 4) * 4 + rg;
        int c = wn * 64 + nt * 16 + (lane & 15);
        ft[r * 128 + c] = acc[mt][nt][rg];
      }
  __syncthreads();
  const int c4 = (tid & 31) * 4;
  const int gcol = tn * 128 + c4;
  float4 bv = make_float4(0.f, 0.f, 0.f, 0.f);
  if (flags & GF_BIAS) bv = *(const float4*)(bias + gcol);
#pragma unroll
  for (int it = 0; it < 16; ++it) {
    int r = it * 8 + (tid >> 5);
    int gr = tm * 128 + r;
    if ((flags & GF_GUARDM) && gr >= M) continue;
    float4 v = *(const float4*)(ft + r * 128 + c4);
    v.x += bv.x; v.y += bv.y; v.z += bv.z; v.w += bv.w;
    *(float4*)(Cm + (size_t)gr * ldc + gcol) = v;
  }
}

__global__ __launch_bounds__(256, 2) void gemm_bt(
    const short* __restrict__ Am, const short* __restrict__ Bm,
    const float* __restrict__ bias, float* __restrict__ Cm,
    int M, int N, int K, int ldc, int flags) {
  __shared__ __align__(16) char smem[65536];
  gemm_tile128(Am, Bm, bias, Cm, M, K, ldc, blockIdx.y, blockIdx.x, flags, smem);
}

// ---------- fused pipe (WGs 0..63) + gemm workers (64..255; pipe WGs join)
struct FusedArgs {
  const short* W0e;
  const short* W0d;
  const short* W1e;
  const short* W1d;
  const short* X;
  const float* b0e;
  const float* b0d;
  const float* b1e;
  const float* b1d;
  short* h0;         // 256 slots, write-once
  short* h1;         // 257 slots (slot 256 = zero pad)
  unsigned* flags;   // [64] packed step flags; flags+64 = worker queue
  const short* Bgem; // outWb [16000][512] fp16
  const float* obias;
  float* Cout;       // d_out fp32 [8128][16000]
  int Tenc, Ttot;
  int workers;       // 0 = pipe-only launch (no worker loop anywhere)
};

__device__ void worker_loop(const FusedArgs& A, char* smem) {
  const int tid = threadIdx.x, wave = tid >> 6;
  int* sQ = (int*)(smem + 131072);
  unsigned* wq = A.flags + 64;
  while (true) {
    if (tid == 0)
      *sQ = (int)__hip_atomic_fetch_add(wq, 1u, __ATOMIC_RELAXED,
                                        __HIP_MEMORY_SCOPE_AGENT);
    __syncthreads();
    int id = *sQ;
    __syncthreads();
    if (id >= 8000) break;
    int tm = id / 125, tn = id - tm * 125;
    unsigned thr = 130 + 2 * tm; if (thr > 255) thr = 255;
    if (wave == 0) poll_l1(A.flags, thr);
    __syncthreads();
    gemm_tile128(A.h1 + (size_t)129 * SLOT, A.Bgem, A.obias, A.Cout,
                 8128, 512, 16000, tm, tn, GF_BIAS | GF_GUARDM, smem);
  }
}

__global__ __launch_bounds__(256, 1) void lstm_fused(FusedArgs A) {
  __shared__ __align__(16) char smem[133120];
  const int tid = threadIdx.x, lane = tid & 63, wave = tid >> 6;
  const int bid = blockIdx.x;

  if (bid >= 64) {            // dedicated logits worker
    worker_loop(A, smem);
    return;
  }

  // ---------------- pipe WG (r19 logic) ----------------
  short* Wlds = (short*)smem;                 // 128 KB
  short* hsm = (short*)(smem + 131072);       // 2 KB
  const int w = bid, layer = w >> 5, wl = w & 31;

  auto stage = [&](const short* Wsrc) {
    for (int i = tid * 8; i < 64 * 1024; i += 256 * 8) {
      int row = i >> 10, k = i & 1023;
      v8s v = *(const v8s*)(Wsrc + (size_t)row * 1024 + k);
      *(v8s*)((char*)Wlds + row * 2048 + ((k * 2) ^ ((row & 7) << 4))) = v;
    }
  };
  stage((layer ? A.W1e : A.W0e) + (size_t)(wl * 64) * 1024);

  const int uu = lane & 15;
  float beV[4], bdV[4];
#pragma unroll
  for (int g = 0; g < 4; ++g) {
    beV[g] = (layer ? A.b1e : A.b0e)[wl * 64 + g * 16 + uu];
    bdV[g] = (layer ? A.b1d : A.b0d)[wl * 64 + g * 16 + uu];
  }
  float creg[4] = {0.f, 0.f, 0.f, 0.f};

  const int arow = wave * 16 + uu;
  const int koff = (lane >> 4) * 8;
  const size_t aoff = (size_t)arow * 512 + koff;
  __syncthreads();

  for (int t = 0; t < A.Ttot; ++t) {
    if (t == A.Tenc) {
      stage((layer ? A.W1d : A.W0d) + (size_t)(wl * 64) * 1024);
      __syncthreads();
    }

    v4f acc[4] = {};

    if (layer) {
      if (wave == 0) poll32(A.flags, 0, (unsigned)(t + 1));
      __syncthreads();
    }
    {
      const short* p1 = (layer ? (A.h0 + (size_t)(t + 1) * SLOT)
                               : (A.X + (size_t)t * SLOT)) + aoff;
      v4u fa[16];
      if (layer) {
#pragma unroll
        for (int kc = 0; kc < 16; ++kc) ld16_sc1(fa[kc], p1 + kc * 32);
      } else {
#pragma unroll
        for (int kc = 0; kc < 16; ++kc) ld16(fa[kc], p1 + kc * 32);
      }
      asm volatile("s_waitcnt vmcnt(0)" ::: "memory");
      __builtin_amdgcn_sched_barrier(0);
#pragma unroll
      for (int kc = 0; kc < 16; ++kc) {
        v8h af = __builtin_bit_cast(v8h, fa[kc]);
        int kg = kc * 32 + koff;
#pragma unroll
        for (int nt = 0; nt < 4; ++nt) {
          int wrow = nt * 16 + uu;
          v8h bh = *(const v8h*)((const char*)Wlds + wrow * 2048 +
                                 ((kg * 2) ^ ((wrow & 7) << 4)));
          acc[nt] = __builtin_amdgcn_mfma_f32_16x16x32_f16(af, bh, acc[nt], 0, 0, 0);
        }
      }
    }

    if (t > 0) {
      if (wave == 0) poll32(A.flags, layer ? 32 : 0, (unsigned)t);
      __syncthreads();
    }
    {
      const short* p2 = ((layer ? A.h1 : A.h0) + (size_t)t * SLOT) + aoff;
      v4u fb[16];
#pragma unroll
      for (int kc = 0; kc < 16; ++kc) ld16_sc1(fb[kc], p2 + kc * 32);
      asm volatile("s_waitcnt vmcnt(0)" ::: "memory");
      __builtin_amdgcn_sched_barrier(0);
#pragma unroll
      for (int kc = 0; kc < 16; ++kc) {
        v8h af = __builtin_bit_cast(v8h, fb[kc]);
        int kg = (kc + 16) * 32 + koff;
#pragma unroll
        for (int nt = 0; nt < 4; ++nt) {
          int wrow = nt * 16 + uu;
          v8h bh = *(const v8h*)((const char*)Wlds + wrow * 2048 +
                                 ((kg * 2) ^ ((wrow & 7) << 4)));
          acc[nt] = __builtin_amdgcn_mfma_f32_16x16x32_f16(af, bh, acc[nt], 0, 0, 0);
        }
      }
    }

    {
      const bool enc = t < A.Tenc;
      const float b0v = enc ? beV[0] : bdV[0];
      const float b1v = enc ? beV[1] : bdV[1];
      const float b2v = enc ? beV[2] : bdV[2];
      const float b3v = enc ? beV[3] : bdV[3];
#pragma unroll
      for (int rg = 0; rg < 4; ++rg) {
        float g0 = acc[0][rg] + b0v;
        float g1 = acc[1][rg] + b1v;
        float g2 = acc[2][rg] + b2v;
        float g3 = acc[3][rg] + b3v;
        float c = sigf(g1) * creg[rg] + sigf(g0) * tanhfast(g2);
        creg[rg] = c;
        float h = sigf(g3) * tanhfast(c);
        int bb = wave * 16 + ((lane >> 4) << 2) + rg;
        hsm[bb * 16 + uu] = f2h(h);
      }
    }
    __syncthreads();

    if (tid < 128) {
      int b = tid >> 1, half = tid & 1;
      v4u d = *(const v4u*)(&hsm[b * 16 + half * 8]);
      short* dst = (layer ? A.h1 : A.h0) + (size_t)(t + 1) * SLOT
                   + b * 512 + wl * 16 + half * 8;
      asm volatile("global_store_dwordx4 %0, %1, off sc1" :: "v"(dst), "v"(d) : "memory");
    }
    asm volatile("s_waitcnt vmcnt(0)" ::: "memory");
    __syncthreads();
    if (tid == 0) {
      unsigned val = (unsigned)(t + 1);
      const unsigned* fp = A.flags + w;
      asm volatile("global_store_dword %0, %1, off sc1" :: "v"(fp), "v"(val) : "memory");
    }
  }

  // pipe done -> join the worker pool for the tail (fused launches only)
  if (A.workers) {
    __syncthreads();
    worker_loop(A, smem);
  }
}

extern "C" void kernel_launch(void* const* d_in, const int* in_sizes, int n_in,
                              void* d_out, int out_size, void* d_ws, size_t ws_size,
                              hipStream_t stream) {
  (void)in_sizes; (void)n_in; (void)out_size;
  const int* src = (const int*)d_in[0];
  const int* trg = (const int*)d_in[1];
  const float* enc_emb = (const float*)d_in[3];
  const float* dec_emb = (const float*)d_in[4];
  const float* enc_Wih = (const float*)d_in[5];
  const float* enc_Whh = (const float*)d_in[6];
  const float* enc_bih = (const float*)d_in[7];
  const float* enc_bhh = (const float*)d_in[8];
  const float* dec_Wih = (const float*)d_in[9];
  const float* dec_Whh = (const float*)d_in[10];
  const float* dec_bih = (const float*)d_in[11];
  const float* dec_bhh = (const float*)d_in[12];
  const float* out_W = (const float*)d_in[13];
  const float* out_b = (const float*)d_in[14];

  char* p = (char*)d_ws;
  auto alloc = [&](size_t sz) { char* r = p; p += (sz + 255) & ~(size_t)255; return r; };
  short* H0 = (short*)alloc((size_t)256 * SLOT * 2);
  short* H1 = (short*)alloc((size_t)257 * SLOT * 2);
  short* W0e = (short*)alloc((size_t)2048 * 1024 * 2);
  short* W0d = (short*)alloc((size_t)2048 * 1024 * 2);
  short* W1e = (short*)alloc((size_t)2048 * 1024 * 2);
  short* W1d = (short*)alloc((size_t)2048 * 1024 * 2);
  short* XO = (short*)alloc((size_t)255 * SLOT * 2);
  float* bE0 = (float*)alloc(2048 * 4);
  float* bE1 = (float*)alloc(2048 * 4);
  float* bD0 = (float*)alloc(2048 * 4);
  float* bD1 = (float*)alloc(2048 * 4);
  unsigned* flags = (unsigned*)alloc(512);   // 64 flags + wq
  size_t common = (size_t)(p - (char*)d_ws);
  const size_t owBytes = (size_t)16000 * 512 * 2;
  bool sepOW = (ws_size == 0) || (ws_size >= common + owBytes + 65536);
  short* outWb = sepOW ? (short*)alloc(owBytes) : XO;

  zero3<<<128, 256, 0, stream>>>(H0, H1, H1 + (size_t)256 * SLOT, flags);
  ConvJobs cj;
  cj.src[0] = enc_Wih;                       cj.dst[0] = W0e; cj.coloff[0] = 0;
  cj.src[1] = enc_Whh;                       cj.dst[1] = W0e; cj.coloff[1] = 512;
  cj.src[2] = dec_Wih;                       cj.dst[2] = W0d; cj.coloff[2] = 0;
  cj.src[3] = dec_Whh;                       cj.dst[3] = W0d; cj.coloff[3] = 512;
  cj.src[4] = enc_Wih + (size_t)2048 * 512;  cj.dst[4] = W1e; cj.coloff[4] = 0;
  cj.src[5] = enc_Whh + (size_t)2048 * 512;  cj.dst[5] = W1e; cj.coloff[5] = 512;
  cj.src[6] = dec_Wih + (size_t)2048 * 512;  cj.dst[6] = W1d; cj.coloff[6] = 0;
  cj.src[7] = dec_Whh + (size_t)2048 * 512;  cj.dst[7] = W1d; cj.coloff[7] = 512;
  conv8<<<dim3(1024, 8), 256, 0, stream>>>(cj);
  BiasJobs bj;
  bj.a[0] = enc_bih;        bj.b[0] = enc_bhh;        bj.o[0] = bE0;
  bj.a[1] = enc_bih + 2048; bj.b[1] = enc_bhh + 2048; bj.o[1] = bE1;
  bj.a[2] = dec_bih;        bj.b[2] = dec_bhh;        bj.o[2] = bD0;
  bj.a[3] = dec_bih + 2048; bj.b[3] = dec_bhh + 2048; bj.o[3] = bD1;
  conv_b4<<<dim3(8, 4), 256, 0, stream>>>(bj);
  embed_all<<<16320, 256, 0, stream>>>(src, trg, enc_emb, dec_emb, XO);
  if (sepOW) conv_ow<<<8000, 256, 0, stream>>>(out_W, outWb);

  FusedArgs fa = {W0e, W0d, W1e, W1d, XO, bE0, bD0, bE1, bD1,
                  H0, H1, flags, outWb, out_b, (float*)d_out, 128, 255,
                  sepOW ? 192 : 0};

  if (sepOW) {
    lstm_fused<<<256, 256, 0, stream>>>(fa);
  } else {
    lstm_fused<<<64, 256, 0, stream>>>(fa);   // pipe only (workers==0)
    conv_ow<<<8000, 256, 0, stream>>>(out_W, outWb);
    gemm_bt<<<dim3(125, 64), 256, 0, stream>>>(H1 + (size_t)129 * SLOT, outWb, out_b,
                                               (float*)d_out, 8128, 16000, 512, 16000,
                                               GF_BIAS | GF_GUARDM);
  }
}

// Round 23
// 2071.687 us; speedup vs baseline: 1.0083x; 1.0083x over previous
//
#include <hip/hip_runtime.h>

// V=16000 E=512 H=512 L=2 S=128 T=128 B=64; gate dim 4H=2048
// r23 = r20 verbatim (empirical best: 2057 us). r21/r22's tail-join and
// adaptive backoff both regressed (+18 us) -> reverted per pre-commitment.
//   grid 256 = 64 pipe WGs + 192 persistent workers. Workers pop tiles
//   (tm-major), poll PACKED L1 flags (2 lines/iter, sleep 64), then run the
//   r18 BK=128 tile + transposed epilogue into d_out. ws-gated; fallback=r19.

typedef __attribute__((ext_vector_type(8))) short v8s;
typedef __attribute__((ext_vector_type(4))) short v4s;
typedef __attribute__((ext_vector_type(8))) _Float16 v8h;
typedef __attribute__((ext_vector_type(4))) float v4f;
typedef __attribute__((ext_vector_type(4))) unsigned int v4u;

#define AS1 __attribute__((address_space(1)))
#define AS3 __attribute__((address_space(3)))

__device__ __forceinline__ short f2h(float x) {
  _Float16 h = (_Float16)x;
  return __builtin_bit_cast(short, h);
}
__device__ __forceinline__ void gload16(const void* g, void* l) {
  __builtin_amdgcn_global_load_lds((const AS1 void*)g, (AS3 void*)l, 16, 0, 0);
}
__device__ __forceinline__ float sigf(float x) { return 1.f / (1.f + __expf(-x)); }
__device__ __forceinline__ float tanhfast(float x) { return 2.f / (1.f + __expf(-2.f * x)) - 1.f; }

__device__ __forceinline__ void ld16_sc1(v4u& d, const void* p) {
  asm volatile("global_load_dwordx4 %0, %1, off sc1" : "=v"(d) : "v"(p) : "memory");
}
__device__ __forceinline__ void ld16(v4u& d, const void* p) {
  asm volatile("global_load_dwordx4 %0, %1, off" : "=v"(d) : "v"(p));
}

// lanes 0..31 check flags[base+lane] >= tgt (packed stride-1)
__device__ __forceinline__ void poll32(const unsigned* flags, int base, unsigned tgt) {
  int lane = threadIdx.x & 63;
  const unsigned* fp = flags + base + (lane & 31);
  while (true) {
    unsigned v;
    asm volatile("global_load_dword %0, %1, off sc1\n\ts_waitcnt vmcnt(0)"
                 : "=v"(v) : "v"(fp) : "memory");
    if (__all((int)((lane >= 32) || (v >= tgt)))) break;
    __builtin_amdgcn_s_sleep(1);
  }
}
// worker poll on L1 flags (packed base 32), long backoff
__device__ __forceinline__ void poll_l1(const unsigned* flags, unsigned thr) {
  int lane = threadIdx.x & 63;
  const unsigned* fp = flags + 32 + (lane & 31);
  while (true) {
    unsigned v;
    asm volatile("global_load_dword %0, %1, off sc1\n\ts_waitcnt vmcnt(0)"
                 : "=v"(v) : "v"(fp) : "memory");
    if (__all((int)((lane >= 32) || (v >= thr)))) break;
    __builtin_amdgcn_s_sleep(64);
  }
}

// ---------- fused prologue kernels ----------
struct ConvJobs {
  const float* src[8];
  short* dst[8];
  int coloff[8];
};
__global__ void conv8(ConvJobs J) {
  int j = blockIdx.y;
  int i = blockIdx.x * 256 + threadIdx.x;
  int r = i >> 7, k4 = (i & 127) * 4;
  int rr = ((r >> 4) & 31) * 64 + (r >> 9) * 16 + (r & 15);
  float4 v = *(const float4*)(J.src[j] + (size_t)r * 512 + k4);
  v4s s; s[0] = f2h(v.x); s[1] = f2h(v.y); s[2] = f2h(v.z); s[3] = f2h(v.w);
  *(v4s*)(J.dst[j] + (size_t)rr * 1024 + J.coloff[j] + k4) = s;
}

__global__ void conv_ow(const float* __restrict__ in, short* __restrict__ out) {
  int i = blockIdx.x * 256 + threadIdx.x;
  if (i >= 16000 * 128) return;
  int r = i >> 7, k4 = (i & 127) * 4;
  float4 v = *(const float4*)(in + (size_t)r * 512 + k4);
  v4s s; s[0] = f2h(v.x); s[1] = f2h(v.y); s[2] = f2h(v.z); s[3] = f2h(v.w);
  *(v4s*)(out + (size_t)r * 512 + k4) = s;
}

struct BiasJobs {
  const float* a[4];
  const float* b[4];
  float* o[4];
};
__global__ void conv_b4(BiasJobs J) {
  int j = blockIdx.y;
  int r = blockIdx.x * 256 + threadIdx.x;
  if (r < 2048)
    J.o[j][((r >> 4) & 31) * 64 + (r >> 9) * 16 + (r & 15)] = J.a[j][r] + J.b[j][r];
}

__global__ void zero3(short* a, short* b, short* c, unsigned* f) {
  int i = blockIdx.x * 256 + threadIdx.x;
  if (i < 32768) { a[i] = 0; b[i] = 0; c[i] = 0; }
  if (i < 128) f[i] = 0;                    // flags[64] + wq
}

__global__ void embed_all(const int* __restrict__ src, const int* __restrict__ trg,
                          const float* __restrict__ ee, const float* __restrict__ de,
                          short* __restrict__ out) {
  int row = blockIdx.x;
  int e = threadIdx.x * 2;
  const float* emb;
  int id;
  if (row < 8192) { id = src[row]; emb = ee; }
  else { id = trg[row - 8192]; emb = de; }
  float2 v = *(const float2*)(emb + (size_t)id * 512 + e);
  unsigned pack = ((unsigned)(unsigned short)f2h(v.y) << 16) | (unsigned short)f2h(v.x);
  *(unsigned*)(out + (size_t)row * 512 + e) = pack;
}

// ---------- GEMM tile: C[M,N] = A[M,K]*B[N,K]^T (+bias), 128x128, BK=128
#define GF_BIAS 2
#define GF_GUARDM 4
#define SLOT 32768

__device__ __forceinline__ void gemm_tile128(
    const short* Am, const short* Bm, const float* bias, float* Cm,
    int M, int K, int ldc, int tm, int tn, int flags, char* smem) {
  short* lA = (short*)smem;
  short* lB = (short*)(smem + 32768);
  const int tid = threadIdx.x, lane = tid & 63, wave = tid >> 6;
  const int wm = wave >> 1, wn = wave & 1;
  v4f acc[4][4] = {};
  const short* Abase = Am + (size_t)tm * 128 * K;
  const short* Bbase = Bm + (size_t)tn * 128 * K;

  for (int kt = 0; kt < K; kt += 128) {
    __syncthreads();
#pragma unroll
    for (int i2 = 0; i2 < 8; ++i2) {
      int c = (wave * 8 + i2) * 64 + lane;
      int row = c >> 4, ch = c & 15;
      int sch = ch ^ (row & 15);
      gload16(Abase + (size_t)row * K + kt + sch * 8, (char*)lA + c * 16);
      gload16(Bbase + (size_t)row * K + kt + sch * 8, (char*)lB + c * 16);
    }
    asm volatile("s_waitcnt vmcnt(0)" ::: "memory");
    __syncthreads();
#pragma unroll
    for (int kc = 0; kc < 4; ++kc) {
      v8h af[4], bh[4];
#pragma unroll
      for (int mt = 0; mt < 4; ++mt) {
        int row = wm * 64 + mt * 16 + (lane & 15);
        af[mt] = *(const v8h*)((const char*)lA + row * 256 +
                               ((kc * 64 + (lane >> 4) * 16) ^ ((row & 15) << 4)));
      }
#pragma unroll
      for (int nt = 0; nt < 4; ++nt) {
        int row = wn * 64 + nt * 16 + (lane & 15);
        bh[nt] = *(const v8h*)((const char*)lB + row * 256 +
                               ((kc * 64 + (lane >> 4) * 16) ^ ((row & 15) << 4)));
      }
#pragma unroll
      for (int mt = 0; mt < 4; ++mt)
#pragma unroll
        for (int nt = 0; nt < 4; ++nt)
          acc[mt][nt] = __builtin_amdgcn_mfma_f32_16x16x32_f16(af[mt], bh[nt], acc[mt][nt], 0, 0, 0);
    }
  }

  __syncthreads();
  float* ft = (float*)smem;
#pragma unroll
  for (int mt = 0; mt < 4; ++mt)
#pragma unroll
    for (int nt = 0; nt < 4; ++nt)
#pragma unroll
      for (int rg = 0; rg < 4; ++rg) {
        int r = wm * 64 + mt * 16 + (lane >> 4) * 4 + rg;
        int c = wn * 64 + nt * 16 + (lane & 15);
        ft[r * 128 + c] = acc[mt][nt][rg];
      }
  __syncthreads();
  const int c4 = (tid & 31) * 4;
  const int gcol = tn * 128 + c4;
  float4 bv = make_float4(0.f, 0.f, 0.f, 0.f);
  if (flags & GF_BIAS) bv = *(const float4*)(bias + gcol);
#pragma unroll
  for (int it = 0; it < 16; ++it) {
    int r = it * 8 + (tid >> 5);
    int gr = tm * 128 + r;
    if ((flags & GF_GUARDM) && gr >= M) continue;
    float4 v = *(const float4*)(ft + r * 128 + c4);
    v.x += bv.x; v.y += bv.y; v.z += bv.z; v.w += bv.w;
    *(float4*)(Cm + (size_t)gr * ldc + gcol) = v;
  }
}

__global__ __launch_bounds__(256, 2) void gemm_bt(
    const short* __restrict__ Am, const short* __restrict__ Bm,
    const float* __restrict__ bias, float* __restrict__ Cm,
    int M, int N, int K, int ldc, int flags) {
  __shared__ __align__(16) char smem[65536];
  gemm_tile128(Am, Bm, bias, Cm, M, K, ldc, blockIdx.y, blockIdx.x, flags, smem);
}

// ---------- fused pipe (WGs 0..63, r19 logic) + gemm workers (64..255)
struct FusedArgs {
  const short* W0e;
  const short* W0d;
  const short* W1e;
  const short* W1d;
  const short* X;
  const float* b0e;
  const float* b0d;
  const float* b1e;
  const float* b1d;
  short* h0;         // 256 slots, write-once
  short* h1;         // 257 slots (slot 256 = zero pad)
  unsigned* flags;   // [64] packed step flags; flags+64 = worker queue
  const short* Bgem; // outWb [16000][512] fp16
  const float* obias;
  float* Cout;       // d_out fp32 [8128][16000]
  int Tenc, Ttot;
  int workers;       // 0 = pipe-only launch
};

__global__ __launch_bounds__(256, 1) void lstm_fused(FusedArgs A) {
  __shared__ __align__(16) char smem[133120];
  const int tid = threadIdx.x, lane = tid & 63, wave = tid >> 6;
  const int bid = blockIdx.x;

  if (bid >= 64) {
    // ---------------- logits worker ----------------
    int* sQ = (int*)(smem + 131072);
    unsigned* wq = A.flags + 64;
    while (true) {
      if (tid == 0)
        *sQ = (int)__hip_atomic_fetch_add(wq, 1u, __ATOMIC_RELAXED,
                                          __HIP_MEMORY_SCOPE_AGENT);
      __syncthreads();
      int id = *sQ;
      __syncthreads();
      if (id >= 8000) break;
      int tm = id / 125, tn = id - tm * 125;
      unsigned thr = 130 + 2 * tm; if (thr > 255) thr = 255;
      if (wave == 0) poll_l1(A.flags, thr);
      __syncthreads();
      gemm_tile128(A.h1 + (size_t)129 * SLOT, A.Bgem, A.obias, A.Cout,
                   8128, 512, 16000, tm, tn, GF_BIAS | GF_GUARDM, smem);
    }
    return;
  }

  // ---------------- pipe WG (r19 logic) ----------------
  short* Wlds = (short*)smem;                 // 128 KB
  short* hsm = (short*)(smem + 131072);       // 2 KB
  const int w = bid, layer = w >> 5, wl = w & 31;

  auto stage = [&](const short* Wsrc) {
    for (int i = tid * 8; i < 64 * 1024; i += 256 * 8) {
      int row = i >> 10, k = i & 1023;
      v8s v = *(const v8s*)(Wsrc + (size_t)row * 1024 + k);
      *(v8s*)((char*)Wlds + row * 2048 + ((k * 2) ^ ((row & 7) << 4))) = v;
    }
  };
  stage((layer ? A.W1e : A.W0e) + (size_t)(wl * 64) * 1024);

  const int uu = lane & 15;
  float beV[4], bdV[4];
#pragma unroll
  for (int g = 0; g < 4; ++g) {
    beV[g] = (layer ? A.b1e : A.b0e)[wl * 64 + g * 16 + uu];
    bdV[g] = (layer ? A.b1d : A.b0d)[wl * 64 + g * 16 + uu];
  }
  float creg[4] = {0.f, 0.f, 0.f, 0.f};

  const int arow = wave * 16 + uu;
  const int koff = (lane >> 4) * 8;
  const size_t aoff = (size_t)arow * 512 + koff;
  __syncthreads();

  for (int t = 0; t < A.Ttot; ++t) {
    if (t == A.Tenc) {
      stage((layer ? A.W1d : A.W0d) + (size_t)(wl * 64) * 1024);
      __syncthreads();
    }

    v4f acc[4] = {};

    if (layer) {
      if (wave == 0) poll32(A.flags, 0, (unsigned)(t + 1));
      __syncthreads();
    }
    {
      const short* p1 = (layer ? (A.h0 + (size_t)(t + 1) * SLOT)
                               : (A.X + (size_t)t * SLOT)) + aoff;
      v4u fa[16];
      if (layer) {
#pragma unroll
        for (int kc = 0; kc < 16; ++kc) ld16_sc1(fa[kc], p1 + kc * 32);
      } else {
#pragma unroll
        for (int kc = 0; kc < 16; ++kc) ld16(fa[kc], p1 + kc * 32);
      }
      asm volatile("s_waitcnt vmcnt(0)" ::: "memory");
      __builtin_amdgcn_sched_barrier(0);
#pragma unroll
      for (int kc = 0; kc < 16; ++kc) {
        v8h af = __builtin_bit_cast(v8h, fa[kc]);
        int kg = kc * 32 + koff;
#pragma unroll
        for (int nt = 0; nt < 4; ++nt) {
          int wrow = nt * 16 + uu;
          v8h bh = *(const v8h*)((const char*)Wlds + wrow * 2048 +
                                 ((kg * 2) ^ ((wrow & 7) << 4)));
          acc[nt] = __builtin_amdgcn_mfma_f32_16x16x32_f16(af, bh, acc[nt], 0, 0, 0);
        }
      }
    }

    if (t > 0) {
      if (wave == 0) poll32(A.flags, layer ? 32 : 0, (unsigned)t);
      __syncthreads();
    }
    {
      const short* p2 = ((layer ? A.h1 : A.h0) + (size_t)t * SLOT) + aoff;
      v4u fb[16];
#pragma unroll
      for (int kc = 0; kc < 16; ++kc) ld16_sc1(fb[kc], p2 + kc * 32);
      asm volatile("s_waitcnt vmcnt(0)" ::: "memory");
      __builtin_amdgcn_sched_barrier(0);
#pragma unroll
      for (int kc = 0; kc < 16; ++kc) {
        v8h af = __builtin_bit_cast(v8h, fb[kc]);
        int kg = (kc + 16) * 32 + koff;
#pragma unroll
        for (int nt = 0; nt < 4; ++nt) {
          int wrow = nt * 16 + uu;
          v8h bh = *(const v8h*)((const char*)Wlds + wrow * 2048 +
                                 ((kg * 2) ^ ((wrow & 7) << 4)));
          acc[nt] = __builtin_amdgcn_mfma_f32_16x16x32_f16(af, bh, acc[nt], 0, 0, 0);
        }
      }
    }

    {
      const bool enc = t < A.Tenc;
      const float b0v = enc ? beV[0] : bdV[0];
      const float b1v = enc ? beV[1] : bdV[1];
      const float b2v = enc ? beV[2] : bdV[2];
      const float b3v = enc ? beV[3] : bdV[3];
#pragma unroll
      for (int rg = 0; rg < 4; ++rg) {
        float g0 = acc[0][rg] + b0v;
        float g1 = acc[1][rg] + b1v;
        float g2 = acc[2][rg] + b2v;
        float g3 = acc[3][rg] + b3v;
        float c = sigf(g1) * creg[rg] + sigf(g0) * tanhfast(g2);
        creg[rg] = c;
        float h = sigf(g3) * tanhfast(c);
        int bb = wave * 16 + ((lane >> 4) << 2) + rg;
        hsm[bb * 16 + uu] = f2h(h);
      }
    }
    __syncthreads();

    if (tid < 128) {
      int b = tid >> 1, half = tid & 1;
      v4u d = *(const v4u*)(&hsm[b * 16 + half * 8]);
      short* dst = (layer ? A.h1 : A.h0) + (size_t)(t + 1) * SLOT
                   + b * 512 + wl * 16 + half * 8;
      asm volatile("global_store_dwordx4 %0, %1, off sc1" :: "v"(dst), "v"(d) : "memory");
    }
    asm volatile("s_waitcnt vmcnt(0)" ::: "memory");
    __syncthreads();
    if (tid == 0) {
      unsigned val = (unsigned)(t + 1);
      const unsigned* fp = A.flags + w;
      asm volatile("global_store_dword %0, %1, off sc1" :: "v"(fp), "v"(val) : "memory");
    }
  }
}

extern "C" void kernel_launch(void* const* d_in, const int* in_sizes, int n_in,
                              void* d_out, int out_size, void* d_ws, size_t ws_size,
                              hipStream_t stream) {
  (void)in_sizes; (void)n_in; (void)out_size;
  const int* src = (const int*)d_in[0];
  const int* trg = (const int*)d_in[1];
  const float* enc_emb = (const float*)d_in[3];
  const float* dec_emb = (const float*)d_in[4];
  const float* enc_Wih = (const float*)d_in[5];
  const float* enc_Whh = (const float*)d_in[6];
  const float* enc_bih = (const float*)d_in[7];
  const float* enc_bhh = (const float*)d_in[8];
  const float* dec_Wih = (const float*)d_in[9];
  const float* dec_Whh = (const float*)d_in[10];
  const float* dec_bih = (const float*)d_in[11];
  const float* dec_bhh = (const float*)d_in[12];
  const float* out_W = (const float*)d_in[13];
  const float* out_b = (const float*)d_in[14];

  char* p = (char*)d_ws;
  auto alloc = [&](size_t sz) { char* r = p; p += (sz + 255) & ~(size_t)255; return r; };
  short* H0 = (short*)alloc((size_t)256 * SLOT * 2);
  short* H1 = (short*)alloc((size_t)257 * SLOT * 2);
  short* W0e = (short*)alloc((size_t)2048 * 1024 * 2);
  short* W0d = (short*)alloc((size_t)2048 * 1024 * 2);
  short* W1e = (short*)alloc((size_t)2048 * 1024 * 2);
  short* W1d = (short*)alloc((size_t)2048 * 1024 * 2);
  short* XO = (short*)alloc((size_t)255 * SLOT * 2);
  float* bE0 = (float*)alloc(2048 * 4);
  float* bE1 = (float*)alloc(2048 * 4);
  float* bD0 = (float*)alloc(2048 * 4);
  float* bD1 = (float*)alloc(2048 * 4);
  unsigned* flags = (unsigned*)alloc(512);   // 64 flags + wq
  size_t common = (size_t)(p - (char*)d_ws);
  const size_t owBytes = (size_t)16000 * 512 * 2;
  bool sepOW = (ws_size == 0) || (ws_size >= common + owBytes + 65536);
  short* outWb = sepOW ? (short*)alloc(owBytes) : XO;

  zero3<<<128, 256, 0, stream>>>(H0, H1, H1 + (size_t)256 * SLOT, flags);
  ConvJobs cj;
  cj.src[0] = enc_Wih;                       cj.dst[0] = W0e; cj.coloff[0] = 0;
  cj.src[1] = enc_Whh;                       cj.dst[1] = W0e; cj.coloff[1] = 512;
  cj.src[2] = dec_Wih;                       cj.dst[2] = W0d; cj.coloff[2] = 0;
  cj.src[3] = dec_Whh;                       cj.dst[3] = W0d; cj.coloff[3] = 512;
  cj.src[4] = enc_Wih + (size_t)2048 * 512;  cj.dst[4] = W1e; cj.coloff[4] = 0;
  cj.src[5] = enc_Whh + (size_t)2048 * 512;  cj.dst[5] = W1e; cj.coloff[5] = 512;
  cj.src[6] = dec_Wih + (size_t)2048 * 512;  cj.dst[6] = W1d; cj.coloff[6] = 0;
  cj.src[7] = dec_Whh + (size_t)2048 * 512;  cj.dst[7] = W1d; cj.coloff[7] = 512;
  conv8<<<dim3(1024, 8), 256, 0, stream>>>(cj);
  BiasJobs bj;
  bj.a[0] = enc_bih;        bj.b[0] = enc_bhh;        bj.o[0] = bE0;
  bj.a[1] = enc_bih + 2048; bj.b[1] = enc_bhh + 2048; bj.o[1] = bE1;
  bj.a[2] = dec_bih;        bj.b[2] = dec_bhh;        bj.o[2] = bD0;
  bj.a[3] = dec_bih + 2048; bj.b[3] = dec_bhh + 2048; bj.o[3] = bD1;
  conv_b4<<<dim3(8, 4), 256, 0, stream>>>(bj);
  embed_all<<<16320, 256, 0, stream>>>(src, trg, enc_emb, dec_emb, XO);
  if (sepOW) conv_ow<<<8000, 256, 0, stream>>>(out_W, outWb);

  FusedArgs fa = {W0e, W0d, W1e, W1d, XO, bE0, bD0, bE1, bD1,
                  H0, H1, flags, outWb, out_b, (float*)d_out, 128, 255,
                  sepOW ? 192 : 0};

  if (sepOW) {
    // pipe + tail-overlapped logits workers in one dispatch
    lstm_fused<<<256, 256, 0, stream>>>(fa);
  } else {
    lstm_fused<<<64, 256, 0, stream>>>(fa);   // pipe only
    conv_ow<<<8000, 256, 0, stream>>>(out_W, outWb);
    gemm_bt<<<dim3(125, 64), 256, 0, stream>>>(H1 + (size_t)129 * SLOT, outWb, out_b,
                                               (float*)d_out, 8128, 16000, 512, 16000,
                                               GF_BIAS | GF_GUARDM);
  }
}